// Round 1
// 1783.207 us; speedup vs baseline: 1.1126x; 1.1126x over previous
//
#include <hip/hip_runtime.h>
#include <hip/hip_bf16.h>

#define RB 16
#define RC 32
#define RN 512
#define RROWS (RB*RC*RN)   // 262144

typedef __attribute__((ext_vector_type(8))) short short8;
typedef __attribute__((ext_vector_type(4))) float floatx4;

__device__ __forceinline__ float bf2f(short s) {
    unsigned u = ((unsigned)(unsigned short)s) << 16;
    float f; __builtin_memcpy(&f, &u, 4); return f;
}
__device__ __forceinline__ short f2bf(float f) {
    __hip_bfloat16 h = __float2bfloat16(f);
    short s; __builtin_memcpy(&s, &h, 2); return s;
}
__device__ __forceinline__ float gelu_tanh(float x) {
    float u = 0.7978845608028654f * (x + 0.044715f * x * x * x);
    return 0.5f * x * (1.0f + tanhf(u));
}

// ---------------- input conversion ----------------
__global__ __launch_bounds__(256) void convert_x_k(const float* __restrict__ x, short* __restrict__ xb) {
    size_t i = ((size_t)blockIdx.x * 256 + threadIdx.x) * 4;
    if (i >= (size_t)RROWS * 192) return;
    const float4 v = *(const float4*)(x + i);
    xb[i + 0] = f2bf(v.x); xb[i + 1] = f2bf(v.y);
    xb[i + 2] = f2bf(v.z); xb[i + 3] = f2bf(v.w);
}

// ---------------- table layout (bf16 elems inside tabs) ----------------
// miT1 [2][192][192]          @ T_MIT1
// miT2 [2][192][192]          @ T_MIT2
// moT1 [2][128][96]           @ T_MOT1   (rows 96..127 zero)
// moT2 [2][128][96]           @ T_MOT2
// WfcTrep [32][128][192]      @ T_WFCREP (WfcT replicated per channel, rows>=96 zero)
// B2all [32][224][192]        @ T_B2ALL  (filtered-irfft192 coeffs per channel; rows>=194 zero)
// B2bT  [32][128][128]        @ T_B2BT   (filtered-irfft96^T per channel; pads zero)
// Rtk192 [192][224]           @ T_RTK    (rfft192 matrix, [t][k]; k>=194 zero)
// R96tk  [96][128]            @ T_R96    (rfft96 matrix,  [t][k]; k>=98 zero)
// A1cos [32][256][128]        @ T_A1     (cos(hs)*Lc[l,h]*w/192; pads zero)
// A2sin [32][256][128]        @ T_A2     (sin(hs)*Lt[l,h]*w/192)
// costable [192][128]         @ T_COS    (cos(ht); h>=97 zero)
// sintable [192][128]         @ T_SIN
enum : int {
    T_MIT1   = 0,
    T_MIT2   = 73728,
    T_MOT1   = 147456,
    T_MOT2   = 172032,
    T_WFCREP = 196608,
    T_B2ALL  = 983040,
    T_B2BT   = 2359296,
    T_RTK    = 2883584,
    T_R96    = 2926592,
    T_A1     = 2938880,
    T_A2     = 3987456,
    T_COS    = 5036032,
    T_SIN    = 5060608,
    T_END    = 5085184
};

__global__ __launch_bounds__(256) void prep_k(short* __restrict__ tabs,
    const float* __restrict__ mi1, const float* __restrict__ mi2,
    const float* __restrict__ mo1, const float* __restrict__ mo2,
    const float* __restrict__ Wfc,
    const float* __restrict__ f1r, const float* __restrict__ f1i,
    const float* __restrict__ f2r, const float* __restrict__ f2i,
    const float* __restrict__ Lc, const float* __restrict__ Lt)
{
    int i = blockIdx.x * 256 + threadIdx.x;
    if (i >= T_END) return;
    const float PI2 = 6.283185307179586f;
    float v = 0.f;
    if (i < T_MOT1) {                       // miT1 / miT2 (transpose of mi)
        int j = i; const float* src = mi1;
        if (j >= T_MIT2) { j -= T_MIT2; src = mi2; }
        int l = j / 36864, r = j % 36864, s = r / 192, t = r % 192;
        v = src[l * 36864 + t * 192 + s];
    } else if (i < T_WFCREP) {              // moT1 / moT2, rows padded to 128
        int j = i - T_MOT1; const float* src = mo1;
        if (j >= 24576) { j -= 24576; src = mo2; }
        int l = j / 12288, r = j % 12288, s = r / 96, t = r % 96;
        v = (s < 96) ? src[l * 9216 + t * 96 + s] : 0.f;
    } else if (i < T_B2ALL) {               // WfcTrep [c][128][192]
        int j = i - T_WFCREP;
        int r = j % 24576; int s = r / 192, t = r % 192;
        v = (s < 96) ? Wfc[t * 96 + s] : 0.f;
    } else if (i < T_B2BT) {                // B2all [c][224][192]
        int j = i - T_B2ALL;
        int c = j / 43008, r = j % 43008, k = r / 192, t = r % 192;
        if (k < 97) {
            float w = (k == 0 || k == 96) ? 1.f : 2.f;
            float s_, c_; sincosf(PI2 * (float)((k * t) % 192) / 192.f, &s_, &c_);
            v = (w / 192.f) * (f1r[c * 97 + k] * c_ - f1i[c * 97 + k] * s_);
        } else if (k < 194) {
            int h = k - 97;
            float w = (h == 0 || h == 96) ? 1.f : 2.f;
            float s_, c_; sincosf(PI2 * (float)((h * t) % 192) / 192.f, &s_, &c_);
            v = -(w / 192.f) * (f1i[c * 97 + h] * c_ + f1r[c * 97 + h] * s_);
        }
    } else if (i < T_RTK) {                 // B2bT [c][128][128]  ([s][k])
        int j = i - T_B2BT;
        int c = j / 16384, r = j % 16384, s = r / 128, k = r % 128;
        if (s < 96) {
            if (k < 49) {
                float w = (k == 0 || k == 48) ? 1.f : 2.f;
                float s_, c_; sincosf(PI2 * (float)((k * s) % 96) / 96.f, &s_, &c_);
                v = (w / 96.f) * (f2r[c * 49 + k] * c_ - f2i[c * 49 + k] * s_);
            } else if (k < 98) {
                int h = k - 49;
                float w = (h == 0 || h == 48) ? 1.f : 2.f;
                float s_, c_; sincosf(PI2 * (float)((h * s) % 96) / 96.f, &s_, &c_);
                v = -(w / 96.f) * (f2i[c * 49 + h] * c_ + f2r[c * 49 + h] * s_);
            }
        }
    } else if (i < T_R96) {                 // Rtk192 [t][k]
        int j = i - T_RTK;
        int t = j / 224, k = j % 224;
        if (k < 97) { float s_, c_; sincosf(PI2 * (float)((k * t) % 192) / 192.f, &s_, &c_); v = c_; }
        else if (k < 194) { int h = k - 97; float s_, c_; sincosf(PI2 * (float)((h * t) % 192) / 192.f, &s_, &c_); v = -s_; }
    } else if (i < T_A1) {                  // R96tk [t][k]
        int j = i - T_R96;
        int t = j / 128, k = j % 128;
        if (k < 49) { float s_, c_; sincosf(PI2 * (float)((k * t) % 96) / 96.f, &s_, &c_); v = c_; }
        else if (k < 98) { int h = k - 49; float s_, c_; sincosf(PI2 * (float)((h * t) % 96) / 96.f, &s_, &c_); v = -s_; }
    } else if (i < T_A2) {                  // A1cos [l][256][128]
        int j = i - T_A1;
        int l = j / 32768, r = j % 32768, s = r / 128, h = r % 128;
        if (s < 192 && h < 97) {
            float w = (h == 0 || h == 96) ? 1.f : 2.f;
            float s_, c_; sincosf(PI2 * (float)((h * s) % 192) / 192.f, &s_, &c_);
            v = (w / 192.f) * Lc[l * 97 + h] * c_;
        }
    } else if (i < T_COS) {                 // A2sin [l][256][128]
        int j = i - T_A2;
        int l = j / 32768, r = j % 32768, s = r / 128, h = r % 128;
        if (s < 192 && h < 97) {
            float w = (h == 0 || h == 96) ? 1.f : 2.f;
            float s_, c_; sincosf(PI2 * (float)((h * s) % 192) / 192.f, &s_, &c_);
            v = (w / 192.f) * Lt[l * 97 + h] * s_;
        }
    } else if (i < T_SIN) {                 // costable [t][h]
        int j = i - T_COS;
        int t = j / 128, h = j % 128;
        if (h < 97) { float s_, c_; sincosf(PI2 * (float)((h * t) % 192) / 192.f, &s_, &c_); v = c_; }
    } else {                                // sintable [t][h]
        int j = i - T_SIN;
        int t = j / 128, h = j % 128;
        if (h < 97) { float s_, c_; sincosf(PI2 * (float)((h * t) % 192) / 192.f, &s_, &c_); v = s_; }
    }
    tabs[i] = f2bf(v);
}

// ---------------- flexible MFMA GEMM, C[M x Nc] = A[M x K] @ BT[n][k]^T ----------------
// NT: block cols / 16.  WS: 0 = 128-row block, 2x2 waves; 1 = 64-row block, 1x4 waves.
// MODE: 0 single; 1 DUAL (A@B1)*gelu(A@B2); 2 SUM2 A1@B1 + A2@B2; 3 ASUM (A1 [+g]*A2)@B1
// GATE: 0 none; 1 A1 *= gate[b, k]; 2 (MODE3) A2 *= gate[b, k]
// EPI: 0 bf16 store; 1 += bf16 X[row,col]; 2 += f32 X[col]; 3 f32 store
// CB: per-channel B: base += ((m0>>cshift)&31) * cbstride
template<int NT, int WS, int MODE, int GATE, int EPI, bool CB>
__global__ __launch_bounds__(256) void g2_k(
    const short* __restrict__ A1, const short* __restrict__ A2,
    const short* __restrict__ BT1, const short* __restrict__ BT2,
    void* __restrict__ Cp, const void* __restrict__ Xp,
    const float* __restrict__ gatep,
    int Nc, int K, int ldc, int cbstride, int cshift)
{
    constexpr int BN = NT * 16;
    constexpr int WN = WS ? 4 : 2;
    constexpr int NF = NT / WN;
    constexpr int BM = WS ? 64 : 128;
    static_assert(NT % WN == 0, "tile split");

    __shared__ short As1[BM * 40];
    __shared__ short As2[(MODE == 2) ? BM * 40 : 8];
    __shared__ short Bs1[BN * 40];
    __shared__ short Bs2[(MODE == 1 || MODE == 2) ? BN * 40 : 8];
    __shared__ float sg[(GATE != 0) ? 192 : 1];

    const int tid = threadIdx.x;
    const int wid = tid >> 6, lane = tid & 63;
    const int wm = WS ? 0 : (wid >> 1);
    const int wn = WS ? wid : (wid & 1);
    const int quad = lane >> 4, cl = lane & 15;
    const int m0 = blockIdx.y * BM, n0 = blockIdx.x * BN;

    const short* Bb1 = BT1;
    const short* Bb2 = BT2;
    if (CB) {
        int c = (m0 >> cshift) & 31;
        Bb1 += (size_t)c * cbstride;
        if (MODE == 1 || MODE == 2) Bb2 += (size_t)c * cbstride;
    }
    if (GATE != 0) {
        int b = m0 >> 14;   // 32*512 rows per batch
        for (int j = tid; j < K; j += 256) sg[j] = gatep[b * K + j];
        __syncthreads();
    }

    floatx4 acc[4][NF] = {};
    floatx4 acc2[(MODE == 1) ? 4 : 1][(MODE == 1) ? NF : 1] = {};

    for (int k0 = 0; k0 < K; k0 += 32) {
        // ---- stage A (BM x 32) ----
        #pragma unroll
        for (int j = 0; j < BM / 64; ++j) {
            int idx = tid + j * 256;
            int r = idx >> 2, kc = (idx & 3) << 3;
            int gk = k0 + kc;
            const size_t ga = (size_t)(m0 + r) * K + gk;
            short8 va = *(const short8*)(A1 + ga);
            if constexpr (MODE == 3) {
                short8 vb = *(const short8*)(A2 + ga);
                #pragma unroll
                for (int e = 0; e < 8; ++e) {
                    float fb = bf2f(vb[e]);
                    if constexpr (GATE == 2) fb *= sg[gk + e];
                    va[e] = f2bf(bf2f(va[e]) + fb);
                }
            } else if constexpr (GATE == 1) {
                #pragma unroll
                for (int e = 0; e < 8; ++e) va[e] = f2bf(bf2f(va[e]) * sg[gk + e]);
            }
            *(short8*)(As1 + r * 40 + kc) = va;
            if constexpr (MODE == 2)
                *(short8*)(As2 + r * 40 + kc) = *(const short8*)(A2 + ga);
        }
        // ---- stage B (BN x 32) ----
        #pragma unroll
        for (int j = 0; j < (BN * 4 + 255) / 256; ++j) {
            int idx = tid + j * 256;
            if ((BN * 4) % 256 != 0 && idx >= BN * 4) continue;
            int n = idx >> 2, kc = (idx & 3) << 3;
            const size_t gb = (size_t)(n0 + n) * K + k0 + kc;
            *(short8*)(Bs1 + n * 40 + kc) = *(const short8*)(Bb1 + gb);
            if constexpr (MODE == 1 || MODE == 2)
                *(short8*)(Bs2 + n * 40 + kc) = *(const short8*)(Bb2 + gb);
        }
        __syncthreads();

        short8 af[4], af2[4];
        #pragma unroll
        for (int mf = 0; mf < 4; ++mf) {
            af[mf] = *(const short8*)(As1 + (wm * 64 + mf * 16 + cl) * 40 + quad * 8);
            if constexpr (MODE == 2)
                af2[mf] = *(const short8*)(As2 + (wm * 64 + mf * 16 + cl) * 40 + quad * 8);
        }
        #pragma unroll
        for (int nf = 0; nf < NF; ++nf) {
            const int brow = (wn * (NF * 16) + nf * 16 + cl) * 40 + quad * 8;
            short8 b1 = *(const short8*)(Bs1 + brow);
            #pragma unroll
            for (int mf = 0; mf < 4; ++mf)
                acc[mf][nf] = __builtin_amdgcn_mfma_f32_16x16x32_bf16(af[mf], b1, acc[mf][nf], 0, 0, 0);
            if constexpr (MODE == 1) {
                short8 b2 = *(const short8*)(Bs2 + brow);
                #pragma unroll
                for (int mf = 0; mf < 4; ++mf)
                    acc2[mf][nf] = __builtin_amdgcn_mfma_f32_16x16x32_bf16(af[mf], b2, acc2[mf][nf], 0, 0, 0);
            }
            if constexpr (MODE == 2) {
                short8 b2 = *(const short8*)(Bs2 + brow);
                #pragma unroll
                for (int mf = 0; mf < 4; ++mf)
                    acc[mf][nf] = __builtin_amdgcn_mfma_f32_16x16x32_bf16(af2[mf], b2, acc[mf][nf], 0, 0, 0);
            }
        }
        __syncthreads();
    }

    #pragma unroll
    for (int nf = 0; nf < NF; ++nf) {
        int col = n0 + wn * (NF * 16) + nf * 16 + cl;
        if (col >= Nc) continue;
        #pragma unroll
        for (int mf = 0; mf < 4; ++mf) {
            #pragma unroll
            for (int r = 0; r < 4; ++r) {
                int row = m0 + wm * 64 + mf * 16 + quad * 4 + r;
                float v = acc[mf][nf][r];
                if constexpr (MODE == 1) v *= gelu_tanh(acc2[mf][nf][r]);
                size_t idx = (size_t)row * ldc + col;
                if constexpr (EPI == 1) v += bf2f(((const short*)Xp)[idx]);
                if constexpr (EPI == 2) v += ((const float*)Xp)[col];
                if constexpr (EPI == 3) ((float*)Cp)[idx] = v;
                else                    ((short*)Cp)[idx] = f2bf(v);
            }
        }
    }
}

// ---------------- time-domain channel mix: xcm = Gc^T x, xtm = Gt^T x ----------------
__global__ __launch_bounds__(128) void mix_k(const short* __restrict__ xb,
    short* __restrict__ xcm, short* __restrict__ xtm,
    const float* __restrict__ Gc, const float* __restrict__ Gt)
{
    __shared__ float sGc[1024], sGt[1024];
    for (int j = threadIdx.x; j < 1024; j += 128) { sGc[j] = Gc[j]; sGt[j] = Gt[j]; }
    __syncthreads();
    int i = blockIdx.x * 128 + threadIdx.x;
    if (i >= RB * RN * 192) return;
    int t = i % 192; int nn = (i / 192) % RN; int b = i / (192 * RN);
    size_t base = ((size_t)b * RC * RN + nn) * 192 + t;
    const size_t cs = (size_t)RN * 192;
    float ac[32], at[32];
    #pragma unroll
    for (int l = 0; l < 32; ++l) { ac[l] = 0.f; at[l] = 0.f; }
    for (int c = 0; c < 32; ++c) {
        float v = bf2f(xb[base + (size_t)c * cs]);
        #pragma unroll
        for (int l = 0; l < 32; ++l) { ac[l] += v * sGc[c * 32 + l]; at[l] += v * sGt[c * 32 + l]; }
    }
    #pragma unroll
    for (int l = 0; l < 32; ++l) {
        xcm[base + (size_t)l * cs] = f2bf(ac[l]);
        xtm[base + (size_t)l * cs] = f2bf(at[l]);
    }
}

// ---------------- attn-gate pipeline ----------------
__global__ __launch_bounds__(256) void meanf_k(const short* __restrict__ z, float* __restrict__ feat, int T) {
    int bc = blockIdx.x; int b = bc >> 5, c = bc & 31;
    int t = threadIdx.x; if (t >= T) return;
    const short* p = z + (size_t)bc * RN * T + t;
    float acc = 0.f;
    #pragma unroll 8
    for (int n = 0; n < RN; ++n) acc += bf2f(p[(size_t)n * T]);
    feat[((size_t)b * T + t) * 32 + c] = acc * (1.0f / RN);
}

__global__ __launch_bounds__(256) void qk_k(const float* __restrict__ feat,
    const float* __restrict__ Wq, const float* __restrict__ Wk,
    float* __restrict__ qb, float* __restrict__ kb, int T)
{
    int i = blockIdx.x * blockDim.x + threadIdx.x;
    if (i >= 16 * T * 64) return;
    int e = i & 63; int t = (i >> 6) % T; int b = i / (64 * T);
    const float* f = feat + ((size_t)b * T + t) * 32;
    float q = 0.f, k = 0.f;
    #pragma unroll
    for (int c = 0; c < 32; ++c) {
        float fv = f[c];
        q += fv * Wq[c * 64 + e];
        k += fv * Wk[c * 64 + e];
    }
    qb[i] = q; kb[i] = k;
}

__global__ __launch_bounds__(64) void gate_k(const float* __restrict__ qb, const float* __restrict__ kb,
                                             float* __restrict__ gate, int T)
{
    __shared__ float s[192];
    int b = blockIdx.x / T, t = blockIdx.x % T;
    int lane = threadIdx.x;
    float qe = qb[((size_t)b * T + t) * 64 + lane];
    for (int t2 = 0; t2 < T; ++t2) {
        float prod = qe * kb[((size_t)b * T + t2) * 64 + lane];
        #pragma unroll
        for (int off = 32; off > 0; off >>= 1) prod += __shfl_xor(prod, off);
        if (lane == 0) s[t2] = prod * 0.125f;
    }
    __syncthreads();
    float m = -1e30f;
    for (int t2 = lane; t2 < T; t2 += 64) m = fmaxf(m, s[t2]);
    #pragma unroll
    for (int off = 32; off > 0; off >>= 1) m = fmaxf(m, __shfl_xor(m, off));
    float sum = 0.f;
    for (int t2 = lane; t2 < T; t2 += 64) sum += __expf(s[t2] - m);
    #pragma unroll
    for (int off = 32; off > 0; off >>= 1) sum += __shfl_xor(sum, off);
    if (lane == 0) {
        float wv = __expf(s[t] - m) / sum;
        gate[b * T + t] = 1.0f + gelu_tanh(wv);
    }
}

// ---------------- orchestration ----------------
extern "C" void kernel_launch(void* const* d_in, const int* in_sizes, int n_in,
                              void* d_out, int out_size, void* d_ws, size_t ws_size,
                              hipStream_t stream)
{
    const float* x   = (const float*)d_in[0];
    const float* Gc  = (const float*)d_in[3];
    const float* Lc  = (const float*)d_in[4];
    const float* Gt  = (const float*)d_in[5];
    const float* Lt  = (const float*)d_in[6];
    const float* f1r = (const float*)d_in[7];
    const float* f1i = (const float*)d_in[8];
    const float* f2r = (const float*)d_in[9];
    const float* f2i = (const float*)d_in[10];
    const float* Wfc = (const float*)d_in[11];
    const float* bfc = (const float*)d_in[12];
    const float* mi1 = (const float*)d_in[13];
    const float* mi2 = (const float*)d_in[14];
    const float* mo1 = (const float*)d_in[15];
    const float* mo2 = (const float*)d_in[16];
    const float* aiq = (const float*)d_in[17];
    const float* aik = (const float*)d_in[18];
    const float* aoq = (const float*)d_in[19];
    const float* aok = (const float*)d_in[20];

    // fp32 scratch
    float* wf = (float*)d_ws;
    size_t fo = 0;
    auto falloc = [&](size_t nf) { float* p = wf + fo; fo += (nf + 3) & ~(size_t)3; return p; };
    float* feat = falloc((size_t)16 * 192 * 32);
    float* qb   = falloc((size_t)16 * 192 * 64);
    float* kb   = falloc((size_t)16 * 192 * 64);
    float* gate = falloc((size_t)16 * 192);
    // bf16 scratch
    short* wb = (short*)(wf + fo);
    size_t bo = 0;
    auto balloc = [&](size_t ne) { short* p = wb + bo; bo += (ne + 7) & ~(size_t)7; return p; };
    constexpr size_t PG = 917504 + 786432 + 393216 + 1572864 + 1572864; // pgemm outputs
    short* tabs = balloc((size_t)T_END + PG);
    short* xb   = balloc((size_t)RROWS * 192);
    short* B1   = balloc((size_t)RROWS * 192);
    short* B2   = balloc((size_t)RROWS * 192);
    short* B3   = balloc((size_t)RROWS * 192);
    if (ws_size < fo * sizeof(float) + bo * sizeof(short)) return;

    short* mid = tabs + T_END;        // [32][128][224]  (B2all @ Wfc)^T-ish
    short* F1  = mid + 917504;        // [32][128][192]  fconv1+Wfc composite, [c][s][t]
    short* F2c = F1 + 786432;         // [32][128][96]   fconv2 composite, [c][s][t]
    short* M1T = F2c + 393216;        // [32][256][192]  cos-path composite, [l][s][t]
    short* M2T = M1T + 1572864;       // [32][256][192]  sin-path composite

    convert_x_k<<<(RROWS * 192 / 4 + 255) / 256, 256, 0, stream>>>(x, xb);
    prep_k<<<(T_END + 255) / 256, 256, 0, stream>>>(tabs, mi1, mi2, mo1, mo2, Wfc, f1r, f1i, f2r, f2i, Lc, Lt);

    // ---- composite precompute (tiny MFMA GEMMs) ----
    // P1: mid[(c,s),k] = sum_t WfcTrep[(c,s),t] * B2all_c[k,t]
    g2_k<14,0,0,0,0,true ><<<dim3(1,32), 256, 0, stream>>>(tabs+T_WFCREP, nullptr, tabs+T_B2ALL, nullptr, mid, nullptr, nullptr, 224, 192, 224, 43008, 7);
    // P2: F1[(c,s),t] = sum_k mid[(c,s),k] * Rtk192[t,k]
    g2_k<12,0,0,0,0,false><<<dim3(1,32), 256, 0, stream>>>(mid, nullptr, tabs+T_RTK, nullptr, F1, nullptr, nullptr, 192, 224, 192, 0, 0);
    // P3: F2[(c,s),t] = sum_k B2bT[(c,s),k] * R96tk[t,k]
    g2_k<6,0,0,0,0,false><<<dim3(1,32), 256, 0, stream>>>(tabs+T_B2BT, nullptr, tabs+T_R96, nullptr, F2c, nullptr, nullptr, 96, 128, 96, 0, 0);
    // P4: M1T[(l,s),t] = sum_h A1cos[(l,s),h] * cos(h t)
    g2_k<12,0,0,0,0,false><<<dim3(1,64), 256, 0, stream>>>(tabs+T_A1, nullptr, tabs+T_COS, nullptr, M1T, nullptr, nullptr, 192, 128, 192, 0, 0);
    // P5: M2T[(l,s),t] = sum_h A2sin[(l,s),h] * sin(h t)
    g2_k<12,0,0,0,0,false><<<dim3(1,64), 256, 0, stream>>>(tabs+T_A2, nullptr, tabs+T_SIN, nullptr, M2T, nullptr, nullptr, 192, 128, 192, 0, 0);

    auto gate_pipeline = [&](short* zbuf, int T, const float* Wq, const float* Wk) {
        meanf_k<<<RB * RC, 256, 0, stream>>>(zbuf, feat, T);
        qk_k<<<(16 * T * 64 + 255) / 256, 256, 0, stream>>>(feat, Wq, Wk, qb, kb, T);
        gate_k<<<16 * T, 64, 0, stream>>>(qb, kb, gate, T);
    };

    // ---- main pipeline ----
    // mix: xcm -> B1, xtm -> B2
    mix_k<<<(RB * RN * 192 + 127) / 128, 128, 0, stream>>>(xb, B1, B2, Gc, Gt);
    // G1: x_c = x + xcm@M1_l + xtm@M2_l  -> B3
    g2_k<12,1,2,0,1,true ><<<dim3(1,4096), 256, 0, stream>>>(B1, B2, M1T, M2T, B3, xb, nullptr, 192, 192, 192, 49152, 9);
    // G2a: gMLP-in layer 0 (dual)  B3 -> B1
    g2_k<12,1,1,0,0,false><<<dim3(1,4096), 256, 0, stream>>>(B3, nullptr, tabs+T_MIT1, tabs+T_MIT2, B1, nullptr, nullptr, 192, 192, 192, 0, 0);
    gate_pipeline(B1, 192, aiq, aik);                     // -> gate (g1)
    // G2b: gMLP-in layer 1, gate g1 folded into A  B1 -> B2
    g2_k<12,1,1,1,0,false><<<dim3(1,4096), 256, 0, stream>>>(B1, nullptr, tabs+T_MIT1+36864, tabs+T_MIT2+36864, B2, nullptr, gate, 192, 192, 192, 0, 0);
    gate_pipeline(B2, 192, aiq + 2048, aik + 2048);       // -> gate (g2)
    // G3: h_y = (x + g2*x_c) @ F1_c + bfc  -> B3 (ldc 96)
    g2_k<6,0,3,2,2,true ><<<dim3(1,2048), 256, 0, stream>>>(xb, B2, F1, nullptr, B3, bfc, gate, 96, 192, 96, 24576, 9);
    // G4a: gMLP-out layer 0 (dual)  B3 -> B1
    g2_k<6,0,1,0,0,false><<<dim3(1,2048), 256, 0, stream>>>(B3, nullptr, tabs+T_MOT1, tabs+T_MOT2, B1, nullptr, nullptr, 96, 96, 96, 0, 0);
    gate_pipeline(B1, 96, aoq, aok);                      // -> gate (g3)
    // G4b: gMLP-out layer 1, gate g3 folded  B1 -> B2
    g2_k<6,0,1,1,0,false><<<dim3(1,2048), 256, 0, stream>>>(B1, nullptr, tabs+T_MOT1+12288, tabs+T_MOT2+12288, B2, nullptr, gate, 96, 96, 96, 0, 0);
    gate_pipeline(B2, 96, aoq + 2048, aok + 2048);        // -> gate (g4)
    // G5: out = (h_y + g4*y_c) @ F2_c  -> d_out (fp32)
    g2_k<6,0,3,2,3,true ><<<dim3(1,2048), 256, 0, stream>>>(B3, B2, F2c, nullptr, d_out, nullptr, gate, 96, 96, 96, 12288, 9);
}

// Round 2
// 1623.039 us; speedup vs baseline: 1.2223x; 1.0987x over previous
//
#include <hip/hip_runtime.h>
#include <hip/hip_bf16.h>

#define RB 16
#define RC 32
#define RN 512
#define RROWS (RB*RC*RN)   // 262144

typedef __attribute__((ext_vector_type(8))) short short8;
typedef __attribute__((ext_vector_type(4))) float floatx4;

__device__ __forceinline__ float bf2f(short s) {
    unsigned u = ((unsigned)(unsigned short)s) << 16;
    float f; __builtin_memcpy(&f, &u, 4); return f;
}
__device__ __forceinline__ short f2bf(float f) {
    __hip_bfloat16 h = __float2bfloat16(f);
    short s; __builtin_memcpy(&s, &h, 2); return s;
}
__device__ __forceinline__ float gelu_tanh(float x) {
    float u = 0.7978845608028654f * (x + 0.044715f * x * x * x);
    return 0.5f * x * (1.0f + tanhf(u));
}

// ---------------- table layout (bf16 elems inside tabs) ----------------
enum : int {
    T_MIT1   = 0,
    T_MIT2   = 73728,
    T_MOT1   = 147456,
    T_MOT2   = 172032,
    T_WFCREP = 196608,
    T_B2ALL  = 983040,
    T_B2BT   = 2359296,
    T_RTK    = 2883584,
    T_R96    = 2926592,
    T_A1     = 2938880,
    T_A2     = 3987456,
    T_COS    = 5036032,
    T_SIN    = 5060608,
    T_GCT    = 5085184,
    T_GTT    = 5086208,
    T_END    = 5087232
};

__global__ __launch_bounds__(256) void prep_k(short* __restrict__ tabs,
    const float* __restrict__ mi1, const float* __restrict__ mi2,
    const float* __restrict__ mo1, const float* __restrict__ mo2,
    const float* __restrict__ Wfc,
    const float* __restrict__ f1r, const float* __restrict__ f1i,
    const float* __restrict__ f2r, const float* __restrict__ f2i,
    const float* __restrict__ Lc, const float* __restrict__ Lt,
    const float* __restrict__ Gc, const float* __restrict__ Gt)
{
    int i = blockIdx.x * 256 + threadIdx.x;
    if (i >= T_END) return;
    const float PI2 = 6.283185307179586f;
    float v = 0.f;
    if (i < T_MOT1) {                       // miT1 / miT2 (transpose of mi)
        int j = i; const float* src = mi1;
        if (j >= T_MIT2) { j -= T_MIT2; src = mi2; }
        int l = j / 36864, r = j % 36864, s = r / 192, t = r % 192;
        v = src[l * 36864 + t * 192 + s];
    } else if (i < T_WFCREP) {              // moT1 / moT2, rows padded to 128
        int j = i - T_MOT1; const float* src = mo1;
        if (j >= 24576) { j -= 24576; src = mo2; }
        int l = j / 12288, r = j % 12288, s = r / 96, t = r % 96;
        v = (s < 96) ? src[l * 9216 + t * 96 + s] : 0.f;
    } else if (i < T_B2ALL) {               // WfcTrep [c][128][192]
        int j = i - T_WFCREP;
        int r = j % 24576; int s = r / 192, t = r % 192;
        v = (s < 96) ? Wfc[t * 96 + s] : 0.f;
    } else if (i < T_B2BT) {                // B2all [c][224][192]
        int j = i - T_B2ALL;
        int c = j / 43008, r = j % 43008, k = r / 192, t = r % 192;
        if (k < 97) {
            float w = (k == 0 || k == 96) ? 1.f : 2.f;
            float s_, c_; sincosf(PI2 * (float)((k * t) % 192) / 192.f, &s_, &c_);
            v = (w / 192.f) * (f1r[c * 97 + k] * c_ - f1i[c * 97 + k] * s_);
        } else if (k < 194) {
            int h = k - 97;
            float w = (h == 0 || h == 96) ? 1.f : 2.f;
            float s_, c_; sincosf(PI2 * (float)((h * t) % 192) / 192.f, &s_, &c_);
            v = -(w / 192.f) * (f1i[c * 97 + h] * c_ + f1r[c * 97 + h] * s_);
        }
    } else if (i < T_RTK) {                 // B2bT [c][128][128]  ([s][k])
        int j = i - T_B2BT;
        int c = j / 16384, r = j % 16384, s = r / 128, k = r % 128;
        if (s < 96) {
            if (k < 49) {
                float w = (k == 0 || k == 48) ? 1.f : 2.f;
                float s_, c_; sincosf(PI2 * (float)((k * s) % 96) / 96.f, &s_, &c_);
                v = (w / 96.f) * (f2r[c * 49 + k] * c_ - f2i[c * 49 + k] * s_);
            } else if (k < 98) {
                int h = k - 49;
                float w = (h == 0 || h == 48) ? 1.f : 2.f;
                float s_, c_; sincosf(PI2 * (float)((h * s) % 96) / 96.f, &s_, &c_);
                v = -(w / 96.f) * (f2i[c * 49 + h] * c_ + f2r[c * 49 + h] * s_);
            }
        }
    } else if (i < T_R96) {                 // Rtk192 [t][k]
        int j = i - T_RTK;
        int t = j / 224, k = j % 224;
        if (k < 97) { float s_, c_; sincosf(PI2 * (float)((k * t) % 192) / 192.f, &s_, &c_); v = c_; }
        else if (k < 194) { int h = k - 97; float s_, c_; sincosf(PI2 * (float)((h * t) % 192) / 192.f, &s_, &c_); v = -s_; }
    } else if (i < T_A1) {                  // R96tk [t][k]
        int j = i - T_R96;
        int t = j / 128, k = j % 128;
        if (k < 49) { float s_, c_; sincosf(PI2 * (float)((k * t) % 96) / 96.f, &s_, &c_); v = c_; }
        else if (k < 98) { int h = k - 49; float s_, c_; sincosf(PI2 * (float)((h * t) % 96) / 96.f, &s_, &c_); v = -s_; }
    } else if (i < T_A2) {                  // A1cos [l][256][128]
        int j = i - T_A1;
        int l = j / 32768, r = j % 32768, s = r / 128, h = r % 128;
        if (s < 192 && h < 97) {
            float w = (h == 0 || h == 96) ? 1.f : 2.f;
            float s_, c_; sincosf(PI2 * (float)((h * s) % 192) / 192.f, &s_, &c_);
            v = (w / 192.f) * Lc[l * 97 + h] * c_;
        }
    } else if (i < T_COS) {                 // A2sin [l][256][128]
        int j = i - T_A2;
        int l = j / 32768, r = j % 32768, s = r / 128, h = r % 128;
        if (s < 192 && h < 97) {
            float w = (h == 0 || h == 96) ? 1.f : 2.f;
            float s_, c_; sincosf(PI2 * (float)((h * s) % 192) / 192.f, &s_, &c_);
            v = (w / 192.f) * Lt[l * 97 + h] * s_;
        }
    } else if (i < T_SIN) {                 // costable [t][h]
        int j = i - T_COS;
        int t = j / 128, h = j % 128;
        if (h < 97) { float s_, c_; sincosf(PI2 * (float)((h * t) % 192) / 192.f, &s_, &c_); v = c_; }
    } else if (i < T_GCT) {                 // sintable [t][h]
        int j = i - T_SIN;
        int t = j / 128, h = j % 128;
        if (h < 97) { float s_, c_; sincosf(PI2 * (float)((h * t) % 192) / 192.f, &s_, &c_); v = s_; }
    } else if (i < T_GTT) {                 // GcT [l][c] = Gc[c][l]
        int j = i - T_GCT; int l = j >> 5, c = j & 31;
        v = Gc[c * 32 + l];
    } else {                                // GtT [l][c] = Gt[c][l]
        int j = i - T_GTT; int l = j >> 5, c = j & 31;
        v = Gt[c * 32 + l];
    }
    tabs[i] = f2bf(v);
}

// ---------------- fused convert + channel mix (MFMA) ----------------
// One block per (b, n): loads x[b,:,n,:] fp32, emits xb (bf16), and
// xcm[b,l,n,:] = sum_c Gc[c,l] x[b,c,n,:],  xtm likewise with Gt.
__global__ __launch_bounds__(256) void mix2_k(const float* __restrict__ x,
    short* __restrict__ xb, short* __restrict__ xcm, short* __restrict__ xtm,
    const short* __restrict__ GcT, const short* __restrict__ GtT)
{
    __shared__ short Xs[32][196];   // padded: bank stride 98 words -> 2-way max on transpose reads

    const int bidx = blockIdx.x;            // 16*512
    const int b = bidx >> 9, n = bidx & 511;
    const int tid = threadIdx.x;
    const size_t cs = (size_t)RN * 192;
    const size_t base = ((size_t)b * 32) * cs + (size_t)n * 192;

    #pragma unroll
    for (int j = 0; j < 6; ++j) {
        int idx = tid + j * 256;            // 0..1535 float4s
        int c = idx / 48, t = (idx % 48) * 4;
        size_t ga = base + (size_t)c * cs + t;
        float4 v = *(const float4*)(x + ga);
        short4 s4;
        s4.x = f2bf(v.x); s4.y = f2bf(v.y); s4.z = f2bf(v.z); s4.w = f2bf(v.w);
        *(short4*)(xb + ga) = s4;
        *(short4*)(&Xs[c][t]) = s4;
    }
    __syncthreads();

    const int wid = tid >> 6, lane = tid & 63;
    const int quad = lane >> 4, cl = lane & 15;

    // B fragments: BT[col=l][k=c] = GT[l][c]
    const short8 bc0 = *(const short8*)(GcT + cl * 32 + quad * 8);
    const short8 bc1 = *(const short8*)(GcT + (cl + 16) * 32 + quad * 8);
    const short8 bt0 = *(const short8*)(GtT + cl * 32 + quad * 8);
    const short8 bt1 = *(const short8*)(GtT + (cl + 16) * 32 + quad * 8);

    floatx4 ac[3][2] = {};
    floatx4 at_[3][2] = {};

    #pragma unroll
    for (int mf = 0; mf < 3; ++mf) {
        int t = wid * 48 + mf * 16 + cl;
        short8 af;
        #pragma unroll
        for (int e = 0; e < 8; ++e) af[e] = Xs[quad * 8 + e][t];  // A[t][c]
        ac[mf][0]  = __builtin_amdgcn_mfma_f32_16x16x32_bf16(af, bc0, ac[mf][0], 0, 0, 0);
        ac[mf][1]  = __builtin_amdgcn_mfma_f32_16x16x32_bf16(af, bc1, ac[mf][1], 0, 0, 0);
        at_[mf][0] = __builtin_amdgcn_mfma_f32_16x16x32_bf16(af, bt0, at_[mf][0], 0, 0, 0);
        at_[mf][1] = __builtin_amdgcn_mfma_f32_16x16x32_bf16(af, bt1, at_[mf][1], 0, 0, 0);
    }

    #pragma unroll
    for (int mf = 0; mf < 3; ++mf) {
        #pragma unroll
        for (int nf = 0; nf < 2; ++nf) {
            int l = nf * 16 + cl;
            int t = wid * 48 + mf * 16 + quad * 4;
            size_t oa = base + (size_t)l * cs + t;
            short4 s1, s2;
            s1.x = f2bf(ac[mf][nf][0]);  s1.y = f2bf(ac[mf][nf][1]);
            s1.z = f2bf(ac[mf][nf][2]);  s1.w = f2bf(ac[mf][nf][3]);
            s2.x = f2bf(at_[mf][nf][0]); s2.y = f2bf(at_[mf][nf][1]);
            s2.z = f2bf(at_[mf][nf][2]); s2.w = f2bf(at_[mf][nf][3]);
            *(short4*)(xcm + oa) = s1;
            *(short4*)(xtm + oa) = s2;
        }
    }
}

// ---------------- flexible MFMA GEMM, C[M x Nc] = A[M x K] @ BT[n][k]^T ----------------
// NT: block cols / 16.  WS: 0 = 128-row block, 2x2 waves; 1 = 64-row block, 1x4 waves.
// MODE: 0 single; 1 DUAL (A@B1)*gelu(A@B2); 2 SUM2 A1@B1 + A2@B2; 3 ASUM (A1 [+g]*A2)@B1
// GATE: 0 none; 1 A1 *= gate[b, k]; 2 (MODE3) A2 *= gate[b, k]
// EPI: 0 bf16 store; 1 += bf16 X[row,col]; 2 += f32 X[col]; 3 f32 store
// CB: per-channel B: base += ((m0>>cshift)&31) * cbstride
// FEAT: accumulate per-(b,col,c) mean over n into featp via atomics
template<int NT, int WS, int MODE, int GATE, int EPI, bool CB, bool FEAT>
__global__ __launch_bounds__(256) void g2_k(
    const short* __restrict__ A1, const short* __restrict__ A2,
    const short* __restrict__ BT1, const short* __restrict__ BT2,
    void* __restrict__ Cp, const void* __restrict__ Xp,
    const float* __restrict__ gatep, float* __restrict__ featp,
    int Nc, int K, int ldc, int cbstride, int cshift)
{
    constexpr int BN = NT * 16;
    constexpr int WN = WS ? 4 : 2;
    constexpr int NF = NT / WN;
    constexpr int BM = WS ? 64 : 128;
    static_assert(NT % WN == 0, "tile split");

    __shared__ short As1[BM * 40];
    __shared__ short As2[(MODE == 2) ? BM * 40 : 8];
    __shared__ short Bs1[BN * 40];
    __shared__ short Bs2[(MODE == 1 || MODE == 2) ? BN * 40 : 8];
    __shared__ float sg[(GATE != 0) ? 192 : 1];

    const int tid = threadIdx.x;
    const int wid = tid >> 6, lane = tid & 63;
    const int wm = WS ? 0 : (wid >> 1);
    const int wn = WS ? wid : (wid & 1);
    const int quad = lane >> 4, cl = lane & 15;
    const int m0 = blockIdx.y * BM, n0 = blockIdx.x * BN;

    const short* Bb1 = BT1;
    const short* Bb2 = BT2;
    if (CB) {
        int c = (m0 >> cshift) & 31;
        Bb1 += (size_t)c * cbstride;
        if (MODE == 1 || MODE == 2) Bb2 += (size_t)c * cbstride;
    }
    if (GATE != 0) {
        int b = m0 >> 14;   // 32*512 rows per batch
        for (int j = tid; j < K; j += 256) sg[j] = gatep[b * K + j];
        __syncthreads();
    }

    floatx4 acc[4][NF] = {};
    floatx4 acc2[(MODE == 1) ? 4 : 1][(MODE == 1) ? NF : 1] = {};

    for (int k0 = 0; k0 < K; k0 += 32) {
        // ---- stage A (BM x 32) ----
        #pragma unroll
        for (int j = 0; j < BM / 64; ++j) {
            int idx = tid + j * 256;
            int r = idx >> 2, kc = (idx & 3) << 3;
            int gk = k0 + kc;
            const size_t ga = (size_t)(m0 + r) * K + gk;
            short8 va = *(const short8*)(A1 + ga);
            if constexpr (MODE == 3) {
                short8 vb = *(const short8*)(A2 + ga);
                #pragma unroll
                for (int e = 0; e < 8; ++e) {
                    float fb = bf2f(vb[e]);
                    if constexpr (GATE == 2) fb *= sg[gk + e];
                    va[e] = f2bf(bf2f(va[e]) + fb);
                }
            } else if constexpr (GATE == 1) {
                #pragma unroll
                for (int e = 0; e < 8; ++e) va[e] = f2bf(bf2f(va[e]) * sg[gk + e]);
            }
            *(short8*)(As1 + r * 40 + kc) = va;
            if constexpr (MODE == 2)
                *(short8*)(As2 + r * 40 + kc) = *(const short8*)(A2 + ga);
        }
        // ---- stage B (BN x 32) ----
        #pragma unroll
        for (int j = 0; j < (BN * 4 + 255) / 256; ++j) {
            int idx = tid + j * 256;
            if ((BN * 4) % 256 != 0 && idx >= BN * 4) continue;
            int n = idx >> 2, kc = (idx & 3) << 3;
            const size_t gb = (size_t)(n0 + n) * K + k0 + kc;
            *(short8*)(Bs1 + n * 40 + kc) = *(const short8*)(Bb1 + gb);
            if constexpr (MODE == 1 || MODE == 2)
                *(short8*)(Bs2 + n * 40 + kc) = *(const short8*)(Bb2 + gb);
        }
        __syncthreads();

        short8 af[4], af2[4];
        #pragma unroll
        for (int mf = 0; mf < 4; ++mf) {
            af[mf] = *(const short8*)(As1 + (wm * 64 + mf * 16 + cl) * 40 + quad * 8);
            if constexpr (MODE == 2)
                af2[mf] = *(const short8*)(As2 + (wm * 64 + mf * 16 + cl) * 40 + quad * 8);
        }
        #pragma unroll
        for (int nf = 0; nf < NF; ++nf) {
            const int brow = (wn * (NF * 16) + nf * 16 + cl) * 40 + quad * 8;
            short8 b1 = *(const short8*)(Bs1 + brow);
            #pragma unroll
            for (int mf = 0; mf < 4; ++mf)
                acc[mf][nf] = __builtin_amdgcn_mfma_f32_16x16x32_bf16(af[mf], b1, acc[mf][nf], 0, 0, 0);
            if constexpr (MODE == 1) {
                short8 b2 = *(const short8*)(Bs2 + brow);
                #pragma unroll
                for (int mf = 0; mf < 4; ++mf)
                    acc2[mf][nf] = __builtin_amdgcn_mfma_f32_16x16x32_bf16(af[mf], b2, acc2[mf][nf], 0, 0, 0);
            }
            if constexpr (MODE == 2) {
                short8 b2 = *(const short8*)(Bs2 + brow);
                #pragma unroll
                for (int mf = 0; mf < 4; ++mf)
                    acc[mf][nf] = __builtin_amdgcn_mfma_f32_16x16x32_bf16(af2[mf], b2, acc[mf][nf], 0, 0, 0);
            }
        }
        __syncthreads();
    }

    float fs[NF];
    #pragma unroll
    for (int nf = 0; nf < NF; ++nf) fs[nf] = 0.f;

    #pragma unroll
    for (int nf = 0; nf < NF; ++nf) {
        int col = n0 + wn * (NF * 16) + nf * 16 + cl;
        if (col >= Nc) continue;
        #pragma unroll
        for (int mf = 0; mf < 4; ++mf) {
            #pragma unroll
            for (int r = 0; r < 4; ++r) {
                int row = m0 + wm * 64 + mf * 16 + quad * 4 + r;
                float v = acc[mf][nf][r];
                if constexpr (MODE == 1) v *= gelu_tanh(acc2[mf][nf][r]);
                size_t idx = (size_t)row * ldc + col;
                if constexpr (EPI == 1) v += bf2f(((const short*)Xp)[idx]);
                if constexpr (EPI == 2) v += ((const float*)Xp)[col];
                if constexpr (EPI == 3) ((float*)Cp)[idx] = v;
                else                    ((short*)Cp)[idx] = f2bf(v);
                if constexpr (FEAT) fs[nf] += v;
            }
        }
    }

    if constexpr (FEAT) {
        int b = m0 >> 14, c = (m0 >> 9) & 31;
        #pragma unroll
        for (int nf = 0; nf < NF; ++nf) {
            float s = fs[nf];
            s += __shfl_xor(s, 16);
            s += __shfl_xor(s, 32);
            if (quad == 0) {
                int col = n0 + wn * (NF * 16) + nf * 16 + cl;
                if (col < Nc)
                    atomicAdd(featp + ((size_t)b * Nc + col) * 32 + c, s * (1.f / 512.f));
            }
        }
    }
}

__global__ __launch_bounds__(256) void zerof_k(float* __restrict__ p, int n) {
    int i = blockIdx.x * 256 + threadIdx.x;
    if (i < n) p[i] = 0.f;
}

// ---------------- attn-gate pipeline ----------------
__global__ __launch_bounds__(256) void qk_k(const float* __restrict__ feat,
    const float* __restrict__ Wq, const float* __restrict__ Wk,
    float* __restrict__ qb, float* __restrict__ kb, int T)
{
    int i = blockIdx.x * blockDim.x + threadIdx.x;
    if (i >= 16 * T * 64) return;
    int e = i & 63; int t = (i >> 6) % T; int b = i / (64 * T);
    const float* f = feat + ((size_t)b * T + t) * 32;
    float q = 0.f, k = 0.f;
    #pragma unroll
    for (int c = 0; c < 32; ++c) {
        float fv = f[c];
        q += fv * Wq[c * 64 + e];
        k += fv * Wk[c * 64 + e];
    }
    qb[i] = q; kb[i] = k;
}

__global__ __launch_bounds__(64) void gate_k(const float* __restrict__ qb, const float* __restrict__ kb,
                                             float* __restrict__ gate, int T)
{
    __shared__ float s[192];
    int b = blockIdx.x / T, t = blockIdx.x % T;
    int lane = threadIdx.x;
    float qe = qb[((size_t)b * T + t) * 64 + lane];
    for (int t2 = 0; t2 < T; ++t2) {
        float prod = qe * kb[((size_t)b * T + t2) * 64 + lane];
        #pragma unroll
        for (int off = 32; off > 0; off >>= 1) prod += __shfl_xor(prod, off);
        if (lane == 0) s[t2] = prod * 0.125f;
    }
    __syncthreads();
    float m = -1e30f;
    for (int t2 = lane; t2 < T; t2 += 64) m = fmaxf(m, s[t2]);
    #pragma unroll
    for (int off = 32; off > 0; off >>= 1) m = fmaxf(m, __shfl_xor(m, off));
    float sum = 0.f;
    for (int t2 = lane; t2 < T; t2 += 64) sum += __expf(s[t2] - m);
    #pragma unroll
    for (int off = 32; off > 0; off >>= 1) sum += __shfl_xor(sum, off);
    if (lane == 0) {
        float wv = __expf(s[t] - m) / sum;
        gate[b * T + t] = 1.0f + gelu_tanh(wv);
    }
}

// ---------------- orchestration ----------------
extern "C" void kernel_launch(void* const* d_in, const int* in_sizes, int n_in,
                              void* d_out, int out_size, void* d_ws, size_t ws_size,
                              hipStream_t stream)
{
    const float* x   = (const float*)d_in[0];
    const float* Gc  = (const float*)d_in[3];
    const float* Lc  = (const float*)d_in[4];
    const float* Gt  = (const float*)d_in[5];
    const float* Lt  = (const float*)d_in[6];
    const float* f1r = (const float*)d_in[7];
    const float* f1i = (const float*)d_in[8];
    const float* f2r = (const float*)d_in[9];
    const float* f2i = (const float*)d_in[10];
    const float* Wfc = (const float*)d_in[11];
    const float* bfc = (const float*)d_in[12];
    const float* mi1 = (const float*)d_in[13];
    const float* mi2 = (const float*)d_in[14];
    const float* mo1 = (const float*)d_in[15];
    const float* mo2 = (const float*)d_in[16];
    const float* aiq = (const float*)d_in[17];
    const float* aik = (const float*)d_in[18];
    const float* aoq = (const float*)d_in[19];
    const float* aok = (const float*)d_in[20];

    // fp32 scratch
    float* wf = (float*)d_ws;
    size_t fo = 0;
    auto falloc = [&](size_t nf) { float* p = wf + fo; fo += (nf + 3) & ~(size_t)3; return p; };
    float* feat = falloc((size_t)16 * 192 * 32);
    float* qb   = falloc((size_t)16 * 192 * 64);
    float* kb   = falloc((size_t)16 * 192 * 64);
    float* gate = falloc((size_t)16 * 192);
    // bf16 scratch
    short* wb = (short*)(wf + fo);
    size_t bo = 0;
    auto balloc = [&](size_t ne) { short* p = wb + bo; bo += (ne + 7) & ~(size_t)7; return p; };
    constexpr size_t PG = 917504 + 786432 + 393216 + 1572864 + 1572864; // pgemm outputs
    short* tabs = balloc((size_t)T_END + PG);
    short* xb   = balloc((size_t)RROWS * 192);
    short* B1   = balloc((size_t)RROWS * 192);
    short* B2   = balloc((size_t)RROWS * 192);
    short* B3   = balloc((size_t)RROWS * 192);
    if (ws_size < fo * sizeof(float) + bo * sizeof(short)) return;

    short* mid = tabs + T_END;        // [32][128][224]
    short* F1  = mid + 917504;        // [32][128][192]  fconv1+Wfc composite, [c][s][t]
    short* F2c = F1 + 786432;         // [32][128][96]   fconv2 composite, [c][s][t]
    short* M1T = F2c + 393216;        // [32][256][192]  cos-path composite, [l][s][t]
    short* M2T = M1T + 1572864;       // [32][256][192]  sin-path composite

    prep_k<<<(T_END + 255) / 256, 256, 0, stream>>>(tabs, mi1, mi2, mo1, mo2, Wfc, f1r, f1i, f2r, f2i, Lc, Lt, Gc, Gt);

    // ---- composite precompute (tiny MFMA GEMMs) ----
    g2_k<14,0,0,0,0,true ,false><<<dim3(1,32), 256, 0, stream>>>(tabs+T_WFCREP, nullptr, tabs+T_B2ALL, nullptr, mid, nullptr, nullptr, nullptr, 224, 192, 224, 43008, 7);
    g2_k<12,0,0,0,0,false,false><<<dim3(1,32), 256, 0, stream>>>(mid, nullptr, tabs+T_RTK, nullptr, F1, nullptr, nullptr, nullptr, 192, 224, 192, 0, 0);
    g2_k<6,0,0,0,0,false,false><<<dim3(1,32), 256, 0, stream>>>(tabs+T_B2BT, nullptr, tabs+T_R96, nullptr, F2c, nullptr, nullptr, nullptr, 96, 128, 96, 0, 0);
    g2_k<12,0,0,0,0,false,false><<<dim3(1,64), 256, 0, stream>>>(tabs+T_A1, nullptr, tabs+T_COS, nullptr, M1T, nullptr, nullptr, nullptr, 192, 128, 192, 0, 0);
    g2_k<12,0,0,0,0,false,false><<<dim3(1,64), 256, 0, stream>>>(tabs+T_A2, nullptr, tabs+T_SIN, nullptr, M2T, nullptr, nullptr, nullptr, 192, 128, 192, 0, 0);

    auto gate_pipeline = [&](int T, const float* Wq, const float* Wk) {
        qk_k<<<(16 * T * 64 + 255) / 256, 256, 0, stream>>>(feat, Wq, Wk, qb, kb, T);
        gate_k<<<16 * T, 64, 0, stream>>>(qb, kb, gate, T);
    };

    // ---- main pipeline ----
    // fused convert + mix: xb, xcm -> B1, xtm -> B2
    mix2_k<<<RB * RN, 256, 0, stream>>>(x, xb, B1, B2, tabs + T_GCT, tabs + T_GTT);
    // G1: x_c = x + xcm@M1_l + xtm@M2_l  -> B3
    g2_k<12,1,2,0,1,true ,false><<<dim3(1,4096), 256, 0, stream>>>(B1, B2, M1T, M2T, B3, xb, nullptr, nullptr, 192, 192, 192, 49152, 9);
    // G2a: gMLP-in layer 0 (dual) + feat accum  B3 -> B1
    zerof_k<<<(16*192*32 + 255)/256, 256, 0, stream>>>(feat, 16*192*32);
    g2_k<12,1,1,0,0,false,true ><<<dim3(1,4096), 256, 0, stream>>>(B3, nullptr, tabs+T_MIT1, tabs+T_MIT2, B1, nullptr, nullptr, feat, 192, 192, 192, 0, 0);
    gate_pipeline(192, aiq, aik);                         // -> gate (g1)
    // G2b: gMLP-in layer 1, gate g1 folded into A + feat  B1 -> B2
    zerof_k<<<(16*192*32 + 255)/256, 256, 0, stream>>>(feat, 16*192*32);
    g2_k<12,1,1,1,0,false,true ><<<dim3(1,4096), 256, 0, stream>>>(B1, nullptr, tabs+T_MIT1+36864, tabs+T_MIT2+36864, B2, nullptr, gate, feat, 192, 192, 192, 0, 0);
    gate_pipeline(192, aiq + 2048, aik + 2048);           // -> gate (g2)
    // G3: h_y = (x + g2*x_c) @ F1_c + bfc  -> B3 (ldc 96)
    g2_k<6,0,3,2,2,true ,false><<<dim3(1,2048), 256, 0, stream>>>(xb, B2, F1, nullptr, B3, bfc, gate, nullptr, 96, 192, 96, 24576, 9);
    // G4a: gMLP-out layer 0 (dual) + feat  B3 -> B1
    zerof_k<<<(16*96*32 + 255)/256, 256, 0, stream>>>(feat, 16*96*32);
    g2_k<6,0,1,0,0,false,true ><<<dim3(1,2048), 256, 0, stream>>>(B3, nullptr, tabs+T_MOT1, tabs+T_MOT2, B1, nullptr, nullptr, feat, 96, 96, 96, 0, 0);
    gate_pipeline(96, aoq, aok);                          // -> gate (g3)
    // G4b: gMLP-out layer 1, gate g3 folded + feat  B1 -> B2
    zerof_k<<<(16*96*32 + 255)/256, 256, 0, stream>>>(feat, 16*96*32);
    g2_k<6,0,1,1,0,false,true ><<<dim3(1,2048), 256, 0, stream>>>(B1, nullptr, tabs+T_MOT1+12288, tabs+T_MOT2+12288, B2, nullptr, gate, feat, 96, 96, 96, 0, 0);
    gate_pipeline(96, aoq + 2048, aok + 2048);            // -> gate (g4)
    // G5: out = (h_y + g4*y_c) @ F2_c  -> d_out (fp32)
    g2_k<6,0,3,2,3,true ,false><<<dim3(1,2048), 256, 0, stream>>>(B3, B2, F2c, nullptr, d_out, nullptr, gate, nullptr, 96, 96, 96, 12288, 9);
}

// Round 3
// 1281.058 us; speedup vs baseline: 1.5487x; 1.2670x over previous
//
#include <hip/hip_runtime.h>
#include <hip/hip_bf16.h>

#define RB 16
#define RC 32
#define RN 512
#define RROWS (RB*RC*RN)   // 262144

typedef __attribute__((ext_vector_type(8))) short short8;
typedef __attribute__((ext_vector_type(4))) float floatx4;

__device__ __forceinline__ float bf2f(short s) {
    unsigned u = ((unsigned)(unsigned short)s) << 16;
    float f; __builtin_memcpy(&f, &u, 4); return f;
}
__device__ __forceinline__ short f2bf(float f) {
    __hip_bfloat16 h = __float2bfloat16(f);
    short s; __builtin_memcpy(&s, &h, 2); return s;
}
// fast gelu: tanh via v_exp_f32 (2/(1+e^{2u})), accurate to ~1e-7 rel
__device__ __forceinline__ float gelu_tanh(float x) {
    float u = 0.7978845608028654f * (x + 0.044715f * x * x * x);
    float t = 1.0f - 2.0f / (1.0f + __expf(2.0f * u));
    return 0.5f * x * (1.0f + t);
}

// ---------------- table layout (bf16 elems inside tabs) ----------------
enum : int {
    T_MIT1   = 0,
    T_MIT2   = 73728,
    T_MOT1   = 147456,
    T_MOT2   = 172032,
    T_WFCREP = 196608,
    T_B2ALL  = 983040,
    T_B2BT   = 2359296,
    T_RTK    = 2883584,
    T_R96    = 2926592,
    T_A1     = 2938880,
    T_A2     = 3987456,
    T_COS    = 5036032,
    T_SIN    = 5060608,
    T_GCT    = 5085184,
    T_GTT    = 5086208,
    T_END    = 5087232
};

__global__ __launch_bounds__(256) void prep_k(short* __restrict__ tabs,
    const float* __restrict__ mi1, const float* __restrict__ mi2,
    const float* __restrict__ mo1, const float* __restrict__ mo2,
    const float* __restrict__ Wfc,
    const float* __restrict__ f1r, const float* __restrict__ f1i,
    const float* __restrict__ f2r, const float* __restrict__ f2i,
    const float* __restrict__ Lc, const float* __restrict__ Lt,
    const float* __restrict__ Gc, const float* __restrict__ Gt)
{
    int i = blockIdx.x * 256 + threadIdx.x;
    if (i >= T_END) return;
    const float PI2 = 6.283185307179586f;
    float v = 0.f;
    if (i < T_MOT1) {                       // miT1 / miT2 (transpose of mi)
        int j = i; const float* src = mi1;
        if (j >= T_MIT2) { j -= T_MIT2; src = mi2; }
        int l = j / 36864, r = j % 36864, s = r / 192, t = r % 192;
        v = src[l * 36864 + t * 192 + s];
    } else if (i < T_WFCREP) {              // moT1 / moT2, rows padded to 128
        int j = i - T_MOT1; const float* src = mo1;
        if (j >= 24576) { j -= 24576; src = mo2; }
        int l = j / 12288, r = j % 12288, s = r / 96, t = r % 96;
        v = (s < 96) ? src[l * 9216 + t * 96 + s] : 0.f;
    } else if (i < T_B2ALL) {               // WfcTrep [c][128][192]
        int j = i - T_WFCREP;
        int r = j % 24576; int s = r / 192, t = r % 192;
        v = (s < 96) ? Wfc[t * 96 + s] : 0.f;
    } else if (i < T_B2BT) {                // B2all [c][224][192]
        int j = i - T_B2ALL;
        int c = j / 43008, r = j % 43008, k = r / 192, t = r % 192;
        if (k < 97) {
            float w = (k == 0 || k == 96) ? 1.f : 2.f;
            float s_, c_; sincosf(PI2 * (float)((k * t) % 192) / 192.f, &s_, &c_);
            v = (w / 192.f) * (f1r[c * 97 + k] * c_ - f1i[c * 97 + k] * s_);
        } else if (k < 194) {
            int h = k - 97;
            float w = (h == 0 || h == 96) ? 1.f : 2.f;
            float s_, c_; sincosf(PI2 * (float)((h * t) % 192) / 192.f, &s_, &c_);
            v = -(w / 192.f) * (f1i[c * 97 + h] * c_ + f1r[c * 97 + h] * s_);
        }
    } else if (i < T_RTK) {                 // B2bT [c][128][128]  ([s][k])
        int j = i - T_B2BT;
        int c = j / 16384, r = j % 16384, s = r / 128, k = r % 128;
        if (s < 96) {
            if (k < 49) {
                float w = (k == 0 || k == 48) ? 1.f : 2.f;
                float s_, c_; sincosf(PI2 * (float)((k * s) % 96) / 96.f, &s_, &c_);
                v = (w / 96.f) * (f2r[c * 49 + k] * c_ - f2i[c * 49 + k] * s_);
            } else if (k < 98) {
                int h = k - 49;
                float w = (h == 0 || h == 48) ? 1.f : 2.f;
                float s_, c_; sincosf(PI2 * (float)((h * s) % 96) / 96.f, &s_, &c_);
                v = -(w / 96.f) * (f2i[c * 49 + h] * c_ + f2r[c * 49 + h] * s_);
            }
        }
    } else if (i < T_R96) {                 // Rtk192 [t][k]
        int j = i - T_RTK;
        int t = j / 224, k = j % 224;
        if (k < 97) { float s_, c_; sincosf(PI2 * (float)((k * t) % 192) / 192.f, &s_, &c_); v = c_; }
        else if (k < 194) { int h = k - 97; float s_, c_; sincosf(PI2 * (float)((h * t) % 192) / 192.f, &s_, &c_); v = -s_; }
    } else if (i < T_A1) {                  // R96tk [t][k]
        int j = i - T_R96;
        int t = j / 128, k = j % 128;
        if (k < 49) { float s_, c_; sincosf(PI2 * (float)((k * t) % 96) / 96.f, &s_, &c_); v = c_; }
        else if (k < 98) { int h = k - 49; float s_, c_; sincosf(PI2 * (float)((h * t) % 96) / 96.f, &s_, &c_); v = -s_; }
    } else if (i < T_A2) {                  // A1cos [l][256][128]
        int j = i - T_A1;
        int l = j / 32768, r = j % 32768, s = r / 128, h = r % 128;
        if (s < 192 && h < 97) {
            float w = (h == 0 || h == 96) ? 1.f : 2.f;
            float s_, c_; sincosf(PI2 * (float)((h * s) % 192) / 192.f, &s_, &c_);
            v = (w / 192.f) * Lc[l * 97 + h] * c_;
        }
    } else if (i < T_COS) {                 // A2sin [l][256][128]
        int j = i - T_A2;
        int l = j / 32768, r = j % 32768, s = r / 128, h = r % 128;
        if (s < 192 && h < 97) {
            float w = (h == 0 || h == 96) ? 1.f : 2.f;
            float s_, c_; sincosf(PI2 * (float)((h * s) % 192) / 192.f, &s_, &c_);
            v = (w / 192.f) * Lt[l * 97 + h] * s_;
        }
    } else if (i < T_SIN) {                 // costable [t][h]
        int j = i - T_COS;
        int t = j / 128, h = j % 128;
        if (h < 97) { float s_, c_; sincosf(PI2 * (float)((h * t) % 192) / 192.f, &s_, &c_); v = c_; }
    } else if (i < T_GCT) {                 // sintable [t][h]
        int j = i - T_SIN;
        int t = j / 128, h = j % 128;
        if (h < 97) { float s_, c_; sincosf(PI2 * (float)((h * t) % 192) / 192.f, &s_, &c_); v = s_; }
    } else if (i < T_GTT) {                 // GcT [l][c] = Gc[c][l]
        int j = i - T_GCT; int l = j >> 5, c = j & 31;
        v = Gc[c * 32 + l];
    } else {                                // GtT [l][c] = Gt[c][l]
        int j = i - T_GTT; int l = j >> 5, c = j & 31;
        v = Gt[c * 32 + l];
    }
    tabs[i] = f2bf(v);
}

// ---------------- fused convert + channel mix (MFMA) ----------------
__global__ __launch_bounds__(256) void mix2_k(const float* __restrict__ x,
    short* __restrict__ xb, short* __restrict__ xcm, short* __restrict__ xtm,
    const short* __restrict__ GcT, const short* __restrict__ GtT)
{
    __shared__ short Xs[32][196];

    const int bidx = blockIdx.x;            // 16*512
    const int b = bidx >> 9, n = bidx & 511;
    const int tid = threadIdx.x;
    const size_t cs = (size_t)RN * 192;
    const size_t base = ((size_t)b * 32) * cs + (size_t)n * 192;

    #pragma unroll
    for (int j = 0; j < 6; ++j) {
        int idx = tid + j * 256;            // 0..1535 float4s
        int c = idx / 48, t = (idx % 48) * 4;
        size_t ga = base + (size_t)c * cs + t;
        float4 v = *(const float4*)(x + ga);
        short4 s4;
        s4.x = f2bf(v.x); s4.y = f2bf(v.y); s4.z = f2bf(v.z); s4.w = f2bf(v.w);
        *(short4*)(xb + ga) = s4;
        *(short4*)(&Xs[c][t]) = s4;
    }
    __syncthreads();

    const int wid = tid >> 6, lane = tid & 63;
    const int quad = lane >> 4, cl = lane & 15;

    const short8 bc0 = *(const short8*)(GcT + cl * 32 + quad * 8);
    const short8 bc1 = *(const short8*)(GcT + (cl + 16) * 32 + quad * 8);
    const short8 bt0 = *(const short8*)(GtT + cl * 32 + quad * 8);
    const short8 bt1 = *(const short8*)(GtT + (cl + 16) * 32 + quad * 8);

    floatx4 ac[3][2] = {};
    floatx4 at_[3][2] = {};

    #pragma unroll
    for (int mf = 0; mf < 3; ++mf) {
        int t = wid * 48 + mf * 16 + cl;
        short8 af;
        #pragma unroll
        for (int e = 0; e < 8; ++e) af[e] = Xs[quad * 8 + e][t];
        ac[mf][0]  = __builtin_amdgcn_mfma_f32_16x16x32_bf16(af, bc0, ac[mf][0], 0, 0, 0);
        ac[mf][1]  = __builtin_amdgcn_mfma_f32_16x16x32_bf16(af, bc1, ac[mf][1], 0, 0, 0);
        at_[mf][0] = __builtin_amdgcn_mfma_f32_16x16x32_bf16(af, bt0, at_[mf][0], 0, 0, 0);
        at_[mf][1] = __builtin_amdgcn_mfma_f32_16x16x32_bf16(af, bt1, at_[mf][1], 0, 0, 0);
    }

    #pragma unroll
    for (int mf = 0; mf < 3; ++mf) {
        #pragma unroll
        for (int nf = 0; nf < 2; ++nf) {
            int l = nf * 16 + cl;
            int t = wid * 48 + mf * 16 + quad * 4;
            size_t oa = base + (size_t)l * cs + t;
            short4 s1, s2;
            s1.x = f2bf(ac[mf][nf][0]);  s1.y = f2bf(ac[mf][nf][1]);
            s1.z = f2bf(ac[mf][nf][2]);  s1.w = f2bf(ac[mf][nf][3]);
            s2.x = f2bf(at_[mf][nf][0]); s2.y = f2bf(at_[mf][nf][1]);
            s2.z = f2bf(at_[mf][nf][2]); s2.w = f2bf(at_[mf][nf][3]);
            *(short4*)(xcm + oa) = s1;
            *(short4*)(xtm + oa) = s2;
        }
    }
}

// ---------------- flexible MFMA GEMM, C[M x Nc] = A[M x K] @ BT[n][k]^T ----------------
// NT: block cols / 16.  WS: 0 = 128-row block, 2x2 waves; 1 = 64-row block, 1x4 waves.
// MODE: 0 single; 1 DUAL (A@B1)*gelu(A@B2); 2 SUM2 A1@B1 + A2@B2; 3 ASUM (A1 [+g]*A2)@B1
// GATE: 0 none; 1 A1 *= gate[b,k]; 2 (MODE3) A2 *= gate[b,k]
// EPI: 0 bf16 store; 1 += bf16 X[row,col]; 2 += f32 X[col]; 3 f32 store
// CB: per-channel B: base += ((m0>>cshift)&31) * cbstride
// FEAT: accumulate per-(b,col,c) mean over n into featp via atomics
// SWZ: 1 = channel-affinity swizzle for grid.y=4096/BM=64 (XCD k serves l%8==k)
// Pipeline: double-buffered LDS, register prefetch of tile t+1 issued before
// computing tile t, single barrier per K-step. Row stride 34 shorts (17 words,
// coprime with 32 banks -> conflict-free ds_read_b128).
template<int NT, int WS, int MODE, int GATE, int EPI, bool CB, bool FEAT, int SWZ>
__global__ __launch_bounds__(256) void g2_k(
    const short* __restrict__ A1, const short* __restrict__ A2,
    const short* __restrict__ BT1, const short* __restrict__ BT2,
    void* __restrict__ Cp, const void* __restrict__ Xp,
    const float* __restrict__ gatep, float* __restrict__ featp,
    int Nc, int K, int ldc, int cbstride, int cshift)
{
    constexpr int BN = NT * 16;
    constexpr int WN = WS ? 4 : 2;
    constexpr int NF = NT / WN;
    constexpr int BM = WS ? 64 : 128;
    constexpr int RS = 34;                   // LDS row stride in shorts
    constexpr int AJ = BM / 64;
    constexpr int BJ = (BN * 4 + 255) / 256;
    constexpr bool BPART = (BN * 4) % 256 != 0;
    static_assert(NT % WN == 0, "tile split");

    __shared__ short As1[2 * BM * RS];
    __shared__ short As2[(MODE == 2) ? 2 * BM * RS : 8];
    __shared__ short Bs1[2 * BN * RS];
    __shared__ short Bs2[(MODE == 1 || MODE == 2) ? 2 * BN * RS : 8];
    __shared__ float sg[(GATE != 0) ? 192 : 1];

    const int tid = threadIdx.x;
    const int wid = tid >> 6, lane = tid & 63;
    const int wm = WS ? 0 : (wid >> 1);
    const int wn = WS ? wid : (wid & 1);
    const int quad = lane >> 4, cl = lane & 15;

    int by = blockIdx.y;
    if constexpr (SWZ == 1) {
        // grid.y = 4096, BM=64: y_log = b*256 + cc*64 + k*8 + i
        // hardware j -> XCD j%8 = k; channel l = cc*8+k -> per-XCD table set 786KB
        int k = by & 7, cc = (by >> 3) & 3, t = by >> 5;
        int b_ = t >> 3, i_ = t & 7;
        by = b_ * 256 + cc * 64 + k * 8 + i_;
    }
    const int m0 = by * BM, n0 = blockIdx.x * BN;

    const short* Bb1 = BT1;
    const short* Bb2 = BT2;
    if (CB) {
        int c = (m0 >> cshift) & 31;
        Bb1 += (size_t)c * cbstride;
        if (MODE == 1 || MODE == 2) Bb2 += (size_t)c * cbstride;
    }
    if (GATE != 0) {
        int b = m0 >> 14;   // 32*512 rows per batch
        for (int j = tid; j < K; j += 256) sg[j] = gatep[b * K + j];
        __syncthreads();
    }

    // prefetch registers
    short8 pa1[AJ], pa2[(MODE == 2 || MODE == 3) ? AJ : 1];
    short8 pb1[BJ], pb2[(MODE == 1 || MODE == 2) ? BJ : 1];

    auto LOAD = [&](int k0) {
        #pragma unroll
        for (int j = 0; j < AJ; ++j) {
            int idx = tid + j * 256;
            int r = idx >> 2, kc = (idx & 3) << 3;
            const size_t ga = (size_t)(m0 + r) * K + k0 + kc;
            pa1[j] = *(const short8*)(A1 + ga);
            if constexpr (MODE == 2 || MODE == 3) pa2[j] = *(const short8*)(A2 + ga);
        }
        #pragma unroll
        for (int j = 0; j < BJ; ++j) {
            int idx = tid + j * 256;
            if (BPART && idx >= BN * 4) continue;
            int n = idx >> 2, kc = (idx & 3) << 3;
            const size_t gb = (size_t)(n0 + n) * K + k0 + kc;
            pb1[j] = *(const short8*)(Bb1 + gb);
            if constexpr (MODE == 1 || MODE == 2) pb2[j] = *(const short8*)(Bb2 + gb);
        }
    };
    auto STORE = [&](int k0, int cur) {
        #pragma unroll
        for (int j = 0; j < AJ; ++j) {
            int idx = tid + j * 256;
            int r = idx >> 2, kc = (idx & 3) << 3;
            short8 va = pa1[j];
            if constexpr (MODE == 3) {
                short8 vb = pa2[j];
                #pragma unroll
                for (int e = 0; e < 8; ++e) {
                    float fb = bf2f(vb[e]);
                    if constexpr (GATE == 2) fb *= sg[k0 + kc + e];
                    va[e] = f2bf(bf2f(va[e]) + fb);
                }
            } else if constexpr (GATE == 1) {
                #pragma unroll
                for (int e = 0; e < 8; ++e) va[e] = f2bf(bf2f(va[e]) * sg[k0 + kc + e]);
            }
            *(short8*)(As1 + cur * BM * RS + r * RS + kc) = va;
            if constexpr (MODE == 2)
                *(short8*)(As2 + cur * BM * RS + r * RS + kc) = pa2[j];
        }
        #pragma unroll
        for (int j = 0; j < BJ; ++j) {
            int idx = tid + j * 256;
            if (BPART && idx >= BN * 4) continue;
            int n = idx >> 2, kc = (idx & 3) << 3;
            *(short8*)(Bs1 + cur * BN * RS + n * RS + kc) = pb1[j];
            if constexpr (MODE == 1 || MODE == 2)
                *(short8*)(Bs2 + cur * BN * RS + n * RS + kc) = pb2[j];
        }
    };

    floatx4 acc[4][NF] = {};
    floatx4 acc2[(MODE == 1) ? 4 : 1][(MODE == 1) ? NF : 1] = {};

    LOAD(0);
    STORE(0, 0);
    __syncthreads();
    int cur = 0;

    for (int k0 = 0; k0 < K; k0 += 32) {
        const bool nxt = (k0 + 32) < K;
        if (nxt) LOAD(k0 + 32);               // issue next tile's global loads

        short8 af[4], af2[4];
        #pragma unroll
        for (int mf = 0; mf < 4; ++mf) {
            af[mf] = *(const short8*)(As1 + cur * BM * RS + (wm * 64 + mf * 16 + cl) * RS + quad * 8);
            if constexpr (MODE == 2)
                af2[mf] = *(const short8*)(As2 + cur * BM * RS + (wm * 64 + mf * 16 + cl) * RS + quad * 8);
        }
        #pragma unroll
        for (int nf = 0; nf < NF; ++nf) {
            const int brow = (wn * (NF * 16) + nf * 16 + cl) * RS + quad * 8;
            short8 b1 = *(const short8*)(Bs1 + cur * BN * RS + brow);
            #pragma unroll
            for (int mf = 0; mf < 4; ++mf)
                acc[mf][nf] = __builtin_amdgcn_mfma_f32_16x16x32_bf16(af[mf], b1, acc[mf][nf], 0, 0, 0);
            if constexpr (MODE == 1) {
                short8 b2 = *(const short8*)(Bs2 + cur * BN * RS + brow);
                #pragma unroll
                for (int mf = 0; mf < 4; ++mf)
                    acc2[mf][nf] = __builtin_amdgcn_mfma_f32_16x16x32_bf16(af[mf], b2, acc2[mf][nf], 0, 0, 0);
            }
            if constexpr (MODE == 2) {
                short8 b2 = *(const short8*)(Bs2 + cur * BN * RS + brow);
                #pragma unroll
                for (int mf = 0; mf < 4; ++mf)
                    acc[mf][nf] = __builtin_amdgcn_mfma_f32_16x16x32_bf16(af2[mf], b2, acc[mf][nf], 0, 0, 0);
            }
        }
        if (nxt) STORE(k0 + 32, cur ^ 1);     // vmcnt drain lands after MFMAs
        __syncthreads();
        cur ^= 1;
    }

    float fs[NF];
    #pragma unroll
    for (int nf = 0; nf < NF; ++nf) fs[nf] = 0.f;

    #pragma unroll
    for (int nf = 0; nf < NF; ++nf) {
        int col = n0 + wn * (NF * 16) + nf * 16 + cl;
        if (col >= Nc) continue;
        #pragma unroll
        for (int mf = 0; mf < 4; ++mf) {
            #pragma unroll
            for (int r = 0; r < 4; ++r) {
                int row = m0 + wm * 64 + mf * 16 + quad * 4 + r;
                float v = acc[mf][nf][r];
                if constexpr (MODE == 1) v *= gelu_tanh(acc2[mf][nf][r]);
                size_t idx = (size_t)row * ldc + col;
                if constexpr (EPI == 1) v += bf2f(((const short*)Xp)[idx]);
                if constexpr (EPI == 2) v += ((const float*)Xp)[col];
                if constexpr (EPI == 3) ((float*)Cp)[idx] = v;
                else                    ((short*)Cp)[idx] = f2bf(v);
                if constexpr (FEAT) fs[nf] += v;
            }
        }
    }

    if constexpr (FEAT) {
        int b = m0 >> 14, c = (m0 >> 9) & 31;
        #pragma unroll
        for (int nf = 0; nf < NF; ++nf) {
            float s = fs[nf];
            s += __shfl_xor(s, 16);
            s += __shfl_xor(s, 32);
            if (quad == 0) {
                int col = n0 + wn * (NF * 16) + nf * 16 + cl;
                if (col < Nc)
                    atomicAdd(featp + ((size_t)b * Nc + col) * 32 + c, s * (1.f / 512.f));
            }
        }
    }
}

__global__ __launch_bounds__(256) void zerof_k(float* __restrict__ p, int n) {
    int i = blockIdx.x * 256 + threadIdx.x;
    if (i < n) p[i] = 0.f;
}

// ---------------- attn-gate pipeline ----------------
__global__ __launch_bounds__(256) void qk_k(const float* __restrict__ feat,
    const float* __restrict__ Wq, const float* __restrict__ Wk,
    float* __restrict__ qb, float* __restrict__ kb, int T)
{
    int i = blockIdx.x * blockDim.x + threadIdx.x;
    if (i >= 16 * T * 64) return;
    int e = i & 63; int t = (i >> 6) % T; int b = i / (64 * T);
    const float* f = feat + ((size_t)b * T + t) * 32;
    float q = 0.f, k = 0.f;
    #pragma unroll
    for (int c = 0; c < 32; ++c) {
        float fv = f[c];
        q += fv * Wq[c * 64 + e];
        k += fv * Wk[c * 64 + e];
    }
    qb[i] = q; kb[i] = k;
}

__global__ __launch_bounds__(64) void gate_k(const float* __restrict__ qb, const float* __restrict__ kb,
                                             float* __restrict__ gate, int T)
{
    __shared__ float s[192];
    int b = blockIdx.x / T, t = blockIdx.x % T;
    int lane = threadIdx.x;
    float qe = qb[((size_t)b * T + t) * 64 + lane];
    for (int t2 = 0; t2 < T; ++t2) {
        float prod = qe * kb[((size_t)b * T + t2) * 64 + lane];
        #pragma unroll
        for (int off = 32; off > 0; off >>= 1) prod += __shfl_xor(prod, off);
        if (lane == 0) s[t2] = prod * 0.125f;
    }
    __syncthreads();
    float m = -1e30f;
    for (int t2 = lane; t2 < T; t2 += 64) m = fmaxf(m, s[t2]);
    #pragma unroll
    for (int off = 32; off > 0; off >>= 1) m = fmaxf(m, __shfl_xor(m, off));
    float sum = 0.f;
    for (int t2 = lane; t2 < T; t2 += 64) sum += __expf(s[t2] - m);
    #pragma unroll
    for (int off = 32; off > 0; off >>= 1) sum += __shfl_xor(sum, off);
    if (lane == 0) {
        float wv = __expf(s[t] - m) / sum;
        gate[b * T + t] = 1.0f + gelu_tanh(wv);
    }
}

// ---------------- orchestration ----------------
extern "C" void kernel_launch(void* const* d_in, const int* in_sizes, int n_in,
                              void* d_out, int out_size, void* d_ws, size_t ws_size,
                              hipStream_t stream)
{
    const float* x   = (const float*)d_in[0];
    const float* Gc  = (const float*)d_in[3];
    const float* Lc  = (const float*)d_in[4];
    const float* Gt  = (const float*)d_in[5];
    const float* Lt  = (const float*)d_in[6];
    const float* f1r = (const float*)d_in[7];
    const float* f1i = (const float*)d_in[8];
    const float* f2r = (const float*)d_in[9];
    const float* f2i = (const float*)d_in[10];
    const float* Wfc = (const float*)d_in[11];
    const float* bfc = (const float*)d_in[12];
    const float* mi1 = (const float*)d_in[13];
    const float* mi2 = (const float*)d_in[14];
    const float* mo1 = (const float*)d_in[15];
    const float* mo2 = (const float*)d_in[16];
    const float* aiq = (const float*)d_in[17];
    const float* aik = (const float*)d_in[18];
    const float* aoq = (const float*)d_in[19];
    const float* aok = (const float*)d_in[20];

    // fp32 scratch
    float* wf = (float*)d_ws;
    size_t fo = 0;
    auto falloc = [&](size_t nf) { float* p = wf + fo; fo += (nf + 3) & ~(size_t)3; return p; };
    float* feat = falloc((size_t)16 * 192 * 32);
    float* qb   = falloc((size_t)16 * 192 * 64);
    float* kb   = falloc((size_t)16 * 192 * 64);
    float* gate = falloc((size_t)16 * 192);
    // bf16 scratch
    short* wb = (short*)(wf + fo);
    size_t bo = 0;
    auto balloc = [&](size_t ne) { short* p = wb + bo; bo += (ne + 7) & ~(size_t)7; return p; };
    constexpr size_t PG = 917504 + 786432 + 393216 + 1572864 + 1572864; // pgemm outputs
    short* tabs = balloc((size_t)T_END + PG);
    short* xb   = balloc((size_t)RROWS * 192);
    short* B1   = balloc((size_t)RROWS * 192);
    short* B2   = balloc((size_t)RROWS * 192);
    short* B3   = balloc((size_t)RROWS * 192);
    if (ws_size < fo * sizeof(float) + bo * sizeof(short)) return;

    short* mid = tabs + T_END;        // [32][128][224]
    short* F1  = mid + 917504;        // [32][128][192]  fconv1+Wfc composite, [c][s][t]
    short* F2c = F1 + 786432;         // [32][128][96]   fconv2 composite, [c][s][t]
    short* M1T = F2c + 393216;        // [32][256][192]  cos-path composite, [l][s][t]
    short* M2T = M1T + 1572864;       // [32][256][192]  sin-path composite

    prep_k<<<(T_END + 255) / 256, 256, 0, stream>>>(tabs, mi1, mi2, mo1, mo2, Wfc, f1r, f1i, f2r, f2i, Lc, Lt, Gc, Gt);

    // ---- composite precompute (tiny MFMA GEMMs) ----
    g2_k<14,0,0,0,0,true ,false,0><<<dim3(1,32), 256, 0, stream>>>(tabs+T_WFCREP, nullptr, tabs+T_B2ALL, nullptr, mid, nullptr, nullptr, nullptr, 224, 192, 224, 43008, 7);
    g2_k<12,0,0,0,0,false,false,0><<<dim3(1,32), 256, 0, stream>>>(mid, nullptr, tabs+T_RTK, nullptr, F1, nullptr, nullptr, nullptr, 192, 224, 192, 0, 0);
    g2_k<6,0,0,0,0,false,false,0><<<dim3(1,32), 256, 0, stream>>>(tabs+T_B2BT, nullptr, tabs+T_R96, nullptr, F2c, nullptr, nullptr, nullptr, 96, 128, 96, 0, 0);
    g2_k<12,0,0,0,0,false,false,0><<<dim3(1,64), 256, 0, stream>>>(tabs+T_A1, nullptr, tabs+T_COS, nullptr, M1T, nullptr, nullptr, nullptr, 192, 128, 192, 0, 0);
    g2_k<12,0,0,0,0,false,false,0><<<dim3(1,64), 256, 0, stream>>>(tabs+T_A2, nullptr, tabs+T_SIN, nullptr, M2T, nullptr, nullptr, nullptr, 192, 128, 192, 0, 0);

    auto gate_pipeline = [&](int T, const float* Wq, const float* Wk) {
        qk_k<<<(16 * T * 64 + 255) / 256, 256, 0, stream>>>(feat, Wq, Wk, qb, kb, T);
        gate_k<<<16 * T, 64, 0, stream>>>(qb, kb, gate, T);
    };

    // ---- main pipeline ----
    // fused convert + mix: xb, xcm -> B1, xtm -> B2
    mix2_k<<<RB * RN, 256, 0, stream>>>(x, xb, B1, B2, tabs + T_GCT, tabs + T_GTT);
    // G1: x_c = x + xcm@M1_l + xtm@M2_l  -> B3  (channel-affinity swizzle)
    g2_k<12,1,2,0,1,true ,false,1><<<dim3(1,4096), 256, 0, stream>>>(B1, B2, M1T, M2T, B3, xb, nullptr, nullptr, 192, 192, 192, 49152, 9);
    // G2a: gMLP-in layer 0 (dual) + feat accum  B3 -> B1
    zerof_k<<<(16*192*32 + 255)/256, 256, 0, stream>>>(feat, 16*192*32);
    g2_k<12,1,1,0,0,false,true ,0><<<dim3(1,4096), 256, 0, stream>>>(B3, nullptr, tabs+T_MIT1, tabs+T_MIT2, B1, nullptr, nullptr, feat, 192, 192, 192, 0, 0);
    gate_pipeline(192, aiq, aik);                         // -> gate (g1)
    // G2b: gMLP-in layer 1, gate g1 folded into A + feat  B1 -> B2
    zerof_k<<<(16*192*32 + 255)/256, 256, 0, stream>>>(feat, 16*192*32);
    g2_k<12,1,1,1,0,false,true ,0><<<dim3(1,4096), 256, 0, stream>>>(B1, nullptr, tabs+T_MIT1+36864, tabs+T_MIT2+36864, B2, nullptr, gate, feat, 192, 192, 192, 0, 0);
    gate_pipeline(192, aiq + 2048, aik + 2048);           // -> gate (g2)
    // G3: h_y = (x + g2*x_c) @ F1_c + bfc  -> B3 (ldc 96)
    g2_k<6,0,3,2,2,true ,false,0><<<dim3(1,2048), 256, 0, stream>>>(xb, B2, F1, nullptr, B3, bfc, gate, nullptr, 96, 192, 96, 24576, 9);
    // G4a: gMLP-out layer 0 (dual) + feat  B3 -> B1
    zerof_k<<<(16*96*32 + 255)/256, 256, 0, stream>>>(feat, 16*96*32);
    g2_k<6,0,1,0,0,false,true ,0><<<dim3(1,2048), 256, 0, stream>>>(B3, nullptr, tabs+T_MOT1, tabs+T_MOT2, B1, nullptr, nullptr, feat, 96, 96, 96, 0, 0);
    gate_pipeline(96, aoq, aok);                          // -> gate (g3)
    // G4b: gMLP-out layer 1, gate g3 folded + feat  B1 -> B2
    zerof_k<<<(16*96*32 + 255)/256, 256, 0, stream>>>(feat, 16*96*32);
    g2_k<6,0,1,1,0,false,true ,0><<<dim3(1,2048), 256, 0, stream>>>(B1, nullptr, tabs+T_MOT1+12288, tabs+T_MOT2+12288, B2, nullptr, gate, feat, 96, 96, 96, 0, 0);
    gate_pipeline(96, aoq + 2048, aok + 2048);            // -> gate (g4)
    // G5: out = (h_y + g4*y_c) @ F2_c  -> d_out (fp32)
    g2_k<6,0,3,2,3,true ,false,0><<<dim3(1,2048), 256, 0, stream>>>(B3, B2, F2c, nullptr, d_out, nullptr, gate, nullptr, 96, 96, 96, 12288, 9);
}